// Round 11
// baseline (2478.197 us; speedup 1.0000x reference)
//
#include <hip/hip_runtime.h>
#include <stdint.h>

#define N_POINTS   400000
#define WIDTH      64
#define M_SAMPLES  1000          // N_POINTS / 400
#define NBLK       64
#define NTHR       512
#define NWAVE      (NTHR / 64)   // 8 waves per block
#define NTOT       (NBLK * NTHR) // 32768 threads -> 2 waves/SIMD on 64 CUs
#define PPT        13            // ceil(400000 / 32768)
#define TAIL_GID   (N_POINTS - (PPT - 1) * NTOT)  // gid < this => k=12 valid
#define EPAD       8             // entry stride = 64 B = ONE cache line, ONE writer
#define NREG       128           // region rotation; reuse distance 128
#define SLOT_WORDS (NREG * NBLK * EPAD)   // 65536 words = 512 KiB

// Entry = FOUR 8-B words on ONE private 64-B line (one writer block; written
// by lanes 0-3 of its wave 0 in a single coalesced store instruction):
//   w0: [63:32] dist f32 bits | [26:19] tag | [18:0] N - idx
//   w1: [63:32] x f32 bits    | [7:0] tag
//   w2: [63:32] y f32 bits    | [7:0] tag
//   w3: [63:32] z f32 bits    | [7:0] tag
// Every word is independently tag-validated: a poller accepts the entry only
// when ALL FOUR tags equal the current tag, and every word with tag t at this
// address was written by the unique iteration with tag t -- so visibility
// skew between words can only cause a retry, never a stale mix (this per-word
// self-validation is what R1's multi-word scheme lacked). Carrying coords in
// the exchange removes the winner-row feats fetch (~600-900 cy cold load)
// from the serial chain entirely.
// Region r = (i-1) & 127; tag = i & 255. Stale words are from i-128 (tag
// differs in bit 7); region r first used at i = r+1 (tag != 0), so the
// init-zeroed words never validate. Overwrite-before-gather impossible
// (R6/R7-verified skew argument). Verified keepers: one-writer-per-line (R5),
// 64-event narrow funnel (R5 vs R6), wide compute (R7), DEPENDENT-SPIN poll
// (R10: same-address pipelining regresses; R9: divergent in-loop fetch
// regresses -- poll body stays uniform, 4 unconditional loads per trip).

__global__ void fps_init(unsigned long long* slot, int* out) {
    int t = blockIdx.x * blockDim.x + threadIdx.x;
    if (t < SLOT_WORDS) slot[t] = 0ull;
    if (t == 0) out[0] = 0;      // seed index
}

// u64 max-reduce via DPP row-scan (HW-verified rounds 1/3/4/5/6/7/9/10).
// STAGES=6 + SRC=63 : max over all 64 lanes, result wave-uniform.
template <int STAGES, int SRCLANE>
__device__ inline unsigned long long wave_scan_max_u64(unsigned long long key) {
    unsigned int lo = (unsigned int)key;
    unsigned int hi = (unsigned int)(key >> 32);
#define FPS_DPP_STAGE(CTRL)                                                     \
    {                                                                           \
        unsigned int nlo = (unsigned int)__builtin_amdgcn_update_dpp(           \
            (int)lo, (int)lo, CTRL, 0xf, 0xf, false);                           \
        unsigned int nhi = (unsigned int)__builtin_amdgcn_update_dpp(           \
            (int)hi, (int)hi, CTRL, 0xf, 0xf, false);                           \
        unsigned long long cand = ((unsigned long long)nhi << 32) | nlo;        \
        unsigned long long cur  = ((unsigned long long)hi  << 32) | lo;         \
        if (cand > cur) { lo = nlo; hi = nhi; }                                 \
    }
    if constexpr (STAGES > 0) FPS_DPP_STAGE(0x111)  // row_shr:1
    if constexpr (STAGES > 1) FPS_DPP_STAGE(0x112)  // row_shr:2
    if constexpr (STAGES > 2) FPS_DPP_STAGE(0x114)  // row_shr:4
    if constexpr (STAGES > 3) FPS_DPP_STAGE(0x118)  // row_shr:8
    if constexpr (STAGES > 4) FPS_DPP_STAGE(0x142)  // row_bcast15
    if constexpr (STAGES > 5) FPS_DPP_STAGE(0x143)  // row_bcast31
#undef FPS_DPP_STAGE
    unsigned int rlo = (unsigned int)__builtin_amdgcn_readlane((int)lo, SRCLANE);
    unsigned int rhi = (unsigned int)__builtin_amdgcn_readlane((int)hi, SRCLANE);
    return ((unsigned long long)rhi << 32) | rlo;
}

// 8-lane (lanes 0..7, one DPP row) max-scan CARRYING xyz payload; returns
// max-key and payload broadcast wave-uniform via readlane(7). Data only flows
// upward within the 16-lane row, so lanes 8-63 (key=0) never contaminate
// lane 7.
__device__ inline void row8_max_with_payload(
    unsigned long long key, float x, float y, float z,
    unsigned long long& okey, float& ox, float& oy, float& oz)
{
    unsigned int lo = (unsigned int)key, hi = (unsigned int)(key >> 32);
#define FPS_DPPP(CTRL)                                                          \
    {                                                                           \
        unsigned int nlo = (unsigned int)__builtin_amdgcn_update_dpp(           \
            (int)lo, (int)lo, CTRL, 0xf, 0xf, false);                           \
        unsigned int nhi = (unsigned int)__builtin_amdgcn_update_dpp(           \
            (int)hi, (int)hi, CTRL, 0xf, 0xf, false);                           \
        float nx = __uint_as_float((unsigned int)__builtin_amdgcn_update_dpp(   \
            (int)__float_as_uint(x), (int)__float_as_uint(x), CTRL, 0xf, 0xf, false)); \
        float ny = __uint_as_float((unsigned int)__builtin_amdgcn_update_dpp(   \
            (int)__float_as_uint(y), (int)__float_as_uint(y), CTRL, 0xf, 0xf, false)); \
        float nz = __uint_as_float((unsigned int)__builtin_amdgcn_update_dpp(   \
            (int)__float_as_uint(z), (int)__float_as_uint(z), CTRL, 0xf, 0xf, false)); \
        unsigned long long cand = ((unsigned long long)nhi << 32) | nlo;        \
        unsigned long long cur  = ((unsigned long long)hi  << 32) | lo;         \
        if (cand > cur) { lo = nlo; hi = nhi; x = nx; y = ny; z = nz; }         \
    }
    FPS_DPPP(0x111)  // row_shr:1
    FPS_DPPP(0x112)  // row_shr:2
    FPS_DPPP(0x114)  // row_shr:4   -> lane7 = max over lanes 0..7
#undef FPS_DPPP
    unsigned int rlo = (unsigned int)__builtin_amdgcn_readlane((int)lo, 7);
    unsigned int rhi = (unsigned int)__builtin_amdgcn_readlane((int)hi, 7);
    okey = ((unsigned long long)rhi << 32) | rlo;
    ox = __uint_as_float((unsigned int)__builtin_amdgcn_readlane((int)__float_as_uint(x), 7));
    oy = __uint_as_float((unsigned int)__builtin_amdgcn_readlane((int)__float_as_uint(y), 7));
    oz = __uint_as_float((unsigned int)__builtin_amdgcn_readlane((int)__float_as_uint(z), 7));
}

// Workspace requirement: SLOT_WORDS * 8 B = 524,288 B in d_ws.
__global__ __launch_bounds__(NTHR)
void fps_main(const float* __restrict__ feats, int* __restrict__ out,
              unsigned long long* __restrict__ slot)
{
    const int tid  = threadIdx.x;
    const int bid  = blockIdx.x;
    const int lane = tid & 63;
    const int wid  = tid >> 6;
    const int gid  = bid * NTHR + tid;

    // Register-resident points + running min squared distance
    float px[PPT], py[PPT], pz[PPT], dd[PPT];
#pragma unroll
    for (int k = 0; k < PPT; k++) {
        int j = gid + k * NTOT;
        if (j < N_POINTS) {
            // row start is 256-B aligned -> one dwordx4 gets x,y,z(,w)
            float4 v = *reinterpret_cast<const float4*>(feats + (size_t)j * WIDTH);
            px[k] = v.x; py[k] = v.y; pz[k] = v.z;
        } else {
            px[k] = 0.f; py[k] = 0.f; pz[k] = 0.f;
        }
        dd[k] = 1e10f;          // matches jnp.full(..., 1e10, f32)
    }

    __shared__ unsigned long long s_key[NWAVE];
    __shared__ float s_x[NWAVE], s_y[NWAVE], s_z[NWAVE];
    __shared__ float s_qx, s_qy, s_qz;

    // Iteration-1 pivot = point 0 (bit-identical source values)
    float qx = feats[0];
    float qy = feats[1];
    float qz = feats[2];

    for (int i = 1; i < M_SAMPLES; i++) {
        const unsigned long long tg = (unsigned long long)(i & 255);
        unsigned long long* cur = slot + (size_t)((i - 1) & (NREG - 1)) * NBLK * EPAD;

        // ---- compute pass: update dd, track per-thread best (dist,idx,XYZ) ----
        float bd = -1.0f, bx = 0.f, by = 0.f, bz = 0.f;
        unsigned int bj = 0;
#pragma unroll
        for (int k = 0; k < PPT; k++) {
            int j = gid + k * NTOT;
            // IEEE ops in reference order; _rn intrinsics block fp-contract
            float dx = __fsub_rn(px[k], qx);
            float dy = __fsub_rn(py[k], qy);
            float dz = __fsub_rn(pz[k], qz);
            float d  = __fadd_rn(__fadd_rn(__fmul_rn(dx, dx), __fmul_rn(dy, dy)),
                                 __fmul_rn(dz, dz));
            float nd = fminf(dd[k], d);
            dd[k] = nd;
            // strict > keeps the smallest j on ties (j ascends with k)
            bool upd = (nd > bd);
            if (k == PPT - 1) upd = upd && (gid < TAIL_GID);
            bd = upd ? nd : bd;
            bj = upd ? (unsigned int)j : bj;
            bx = upd ? px[k] : bx;
            by = upd ? py[k] : by;
            bz = upd ? pz[k] : bz;
        }
        unsigned long long key =
            ((unsigned long long)__float_as_uint(bd) << 32) |
            (tg << 19) |
            (unsigned long long)(N_POINTS - bj);

        // ---- per-wave DPP reduce (key only); winner lane stages key+xyz ----
        unsigned long long wmax = wave_scan_max_u64<6, 63>(key);
        if (key == wmax) {       // exactly one lane (indices unique in wave)
            s_key[wid] = wmax;
            s_x[wid] = bx; s_y[wid] = by; s_z[wid] = bz;
        }
        __syncthreads();

        if (wid == 0) {
            // ---- block reduce: 8 wave entries -> key+xyz, wave-uniform ----
            unsigned long long bk = (lane < NWAVE) ? s_key[lane] : 0ull;
            float lx = (lane < NWAVE) ? s_x[lane] : 0.f;
            float ly = (lane < NWAVE) ? s_y[lane] : 0.f;
            float lz = (lane < NWAVE) ? s_z[lane] : 0.f;
            unsigned long long blockkey; float wx, wy, wz;
            row8_max_with_payload(bk, lx, ly, lz, blockkey, wx, wy, wz);

            // ---- store: lanes 0-3 write the 4 entry words in ONE coalesced
            //      32-B transaction to this block's private line ----
            unsigned long long w =
                (lane == 0) ? blockkey :
                (lane == 1) ? (((unsigned long long)__float_as_uint(wx) << 32) | tg) :
                (lane == 2) ? (((unsigned long long)__float_as_uint(wy) << 32) | tg) :
                              (((unsigned long long)__float_as_uint(wz) << 32) | tg);
            if (lane < 4)
                __hip_atomic_store(&cur[(size_t)bid * EPAD + lane], w,
                                   __ATOMIC_RELAXED, __HIP_MEMORY_SCOPE_AGENT);

            // ---- DEPENDENT-SPIN poll (R7-verified shape): lane l waits on
            //      block l's entry; 4 unconditional loads per trip (uniform
            //      body, statically countable vmcnt); accept only when all
            //      four tags match ----
            const unsigned long long* lp = cur + (size_t)lane * EPAD;
            unsigned long long w0, w1, w2, w3;
            for (;;) {
                w0 = __hip_atomic_load(lp + 0, __ATOMIC_RELAXED, __HIP_MEMORY_SCOPE_AGENT);
                w1 = __hip_atomic_load(lp + 1, __ATOMIC_RELAXED, __HIP_MEMORY_SCOPE_AGENT);
                w2 = __hip_atomic_load(lp + 2, __ATOMIC_RELAXED, __HIP_MEMORY_SCOPE_AGENT);
                w3 = __hip_atomic_load(lp + 3, __ATOMIC_RELAXED, __HIP_MEMORY_SCOPE_AGENT);
                if ((((w0 >> 19) & 255ull) == tg) & ((w1 & 255ull) == tg) &
                    ((w2 & 255ull) == tg) & ((w3 & 255ull) == tg)) break;
            }

            // ---- final reduce on keys; the winning lane already HOLDS the
            //      winner's coords (no feats fetch anywhere) ----
            unsigned long long win = wave_scan_max_u64<6, 63>(w0);
            if (w0 == win) {     // exactly one lane (indices unique globally)
                s_qx = __uint_as_float((unsigned int)(w1 >> 32));
                s_qy = __uint_as_float((unsigned int)(w2 >> 32));
                s_qz = __uint_as_float((unsigned int)(w3 >> 32));
                if (bid == 0)
                    out[i] = (int)(N_POINTS - (unsigned int)(w0 & 0x7FFFFull));
            }
        }
        // Waves 1..7 wait here while wave 0 runs the exchange
        __syncthreads();
        qx = s_qx; qy = s_qy; qz = s_qz;
    }
}

extern "C" void kernel_launch(void* const* d_in, const int* in_sizes, int n_in,
                              void* d_out, int out_size, void* d_ws, size_t ws_size,
                              hipStream_t stream) {
    const float* feats = (const float*)d_in[0];
    int* out = (int*)d_out;
    unsigned long long* slot = (unsigned long long*)d_ws;  // 512 KiB used

    fps_init<<<(SLOT_WORDS + 255) / 256, 256, 0, stream>>>(slot, out);
    // 64 blocks x 512 thr: all blocks trivially co-resident
    fps_main<<<NBLK, NTHR, 0, stream>>>(feats, out, slot);
}

// Round 12
// 2390.224 us; speedup vs baseline: 1.0368x; 1.0368x over previous
//
#include <hip/hip_runtime.h>
#include <stdint.h>

#define N_POINTS   400000
#define WIDTH      64
#define M_SAMPLES  1000          // N_POINTS / 400
#define NBLK       64
#define NTHR       512
#define NWAVE      (NTHR / 64)   // 8 waves per block
#define NTOT       (NBLK * NTHR) // 32768 threads -> 2 waves/SIMD on 64 CUs
#define PPT        13            // ceil(400000 / 32768)
#define TAIL_GID   (N_POINTS - (PPT - 1) * NTOT)  // gid < this => k=12 valid
#define NREP       4             // entry replicated on 4 private lines
#define EWORDS     (NREP * 8)    // 32 u64 words = 256 B per block entry
#define NREG       128           // region rotation; reuse distance 128
#define SLOT_WORDS (NREG * NBLK * EWORDS)   // 262144 words = 2 MiB

// Entry word (replicated x4, one per private 64-B line, all by ONE writer
// block in a single 4-lane store instruction):
//   [63:32] dist f32 bits (non-negative -> monotone u32)
//   [26:19] tag = i & 255
//   [18:0]  N - idx (1..400000 < 2^19; ties -> lowest idx wins)
// Replication exists ONLY to give the poller 4 DISTINCT addresses: concurrent
// same-address loads MSHR-merge (R10: pipelined same-address poll regressed),
// but round-robin over 4 lines samples the entry every ~L/4 instead of every
// ~L. Phase offsets are established once by s_sleep-staggered initial issues
// and then self-maintained by each address's own vmcnt-gated reissue.
// Region r = (i-1) & 127; tag = i & 255. Stale words are from i-128 (tag
// differs in bit 7); every block rewrites its lines each region pass, and
// region r is first written at i = r+1 (tag != 0), so init zeros never
// validate. Overwrite-before-gather impossible (R6/R7-verified skew argument).
// Verified keepers: one-writer-per-line (R5), 64-event funnel (R5 vs R6),
// wide compute (R7), uniform poll body with no divergent in-loop fetch (R9).

__global__ void fps_init(unsigned long long* slot, int* out) {
    int t = blockIdx.x * blockDim.x + threadIdx.x;
    if (t < SLOT_WORDS) slot[t] = 0ull;
    if (t == 0) out[0] = 0;      // seed index
}

// u64 max-reduce via DPP row-scan (HW-verified rounds 1/3/4/5/6/7/9/10/11).
// STAGES=3 + SRC=7  : max over lanes 0..7   (block-level, 8 wave maxima)
// STAGES=6 + SRC=63 : max over all 64 lanes
template <int STAGES, int SRCLANE>
__device__ inline unsigned long long wave_scan_max_u64(unsigned long long key) {
    unsigned int lo = (unsigned int)key;
    unsigned int hi = (unsigned int)(key >> 32);
#define FPS_DPP_STAGE(CTRL)                                                     \
    {                                                                           \
        unsigned int nlo = (unsigned int)__builtin_amdgcn_update_dpp(           \
            (int)lo, (int)lo, CTRL, 0xf, 0xf, false);                           \
        unsigned int nhi = (unsigned int)__builtin_amdgcn_update_dpp(           \
            (int)hi, (int)hi, CTRL, 0xf, 0xf, false);                           \
        unsigned long long cand = ((unsigned long long)nhi << 32) | nlo;        \
        unsigned long long cur  = ((unsigned long long)hi  << 32) | lo;         \
        if (cand > cur) { lo = nlo; hi = nhi; }                                 \
    }
    if constexpr (STAGES > 0) FPS_DPP_STAGE(0x111)  // row_shr:1
    if constexpr (STAGES > 1) FPS_DPP_STAGE(0x112)  // row_shr:2
    if constexpr (STAGES > 2) FPS_DPP_STAGE(0x114)  // row_shr:4
    if constexpr (STAGES > 3) FPS_DPP_STAGE(0x118)  // row_shr:8
    if constexpr (STAGES > 4) FPS_DPP_STAGE(0x142)  // row_bcast15
    if constexpr (STAGES > 5) FPS_DPP_STAGE(0x143)  // row_bcast31
#undef FPS_DPP_STAGE
    unsigned int rlo = (unsigned int)__builtin_amdgcn_readlane((int)lo, SRCLANE);
    unsigned int rhi = (unsigned int)__builtin_amdgcn_readlane((int)hi, SRCLANE);
    return ((unsigned long long)rhi << 32) | rlo;
}

#define FPS_AL(P) __hip_atomic_load((P), __ATOMIC_RELAXED, __HIP_MEMORY_SCOPE_AGENT)

// Workspace requirement: SLOT_WORDS * 8 B = 2,097,152 B in d_ws.
__global__ __launch_bounds__(NTHR)
void fps_main(const float* __restrict__ feats, int* __restrict__ out,
              unsigned long long* __restrict__ slot)
{
    const int tid  = threadIdx.x;
    const int bid  = blockIdx.x;
    const int lane = tid & 63;
    const int wid  = tid >> 6;
    const int gid  = bid * NTHR + tid;

    // Register-resident points + running min squared distance
    float px[PPT], py[PPT], pz[PPT], dd[PPT];
#pragma unroll
    for (int k = 0; k < PPT; k++) {
        int j = gid + k * NTOT;
        if (j < N_POINTS) {
            // row start is 256-B aligned -> one dwordx4 gets x,y,z(,w)
            float4 v = *reinterpret_cast<const float4*>(feats + (size_t)j * WIDTH);
            px[k] = v.x; py[k] = v.y; pz[k] = v.z;
        } else {
            px[k] = 0.f; py[k] = 0.f; pz[k] = 0.f;
        }
        dd[k] = 1e10f;          // matches jnp.full(..., 1e10, f32)
    }

    __shared__ unsigned long long s_wmax[NWAVE];
    __shared__ float s_qx, s_qy, s_qz;

    // Iteration-1 pivot = point 0 (bit-identical source values)
    float qx = feats[0];
    float qy = feats[1];
    float qz = feats[2];

    for (int i = 1; i < M_SAMPLES; i++) {
        const unsigned long long tg = (unsigned long long)(i & 255);
        unsigned long long* cur =
            slot + (size_t)((i - 1) & (NREG - 1)) * NBLK * EWORDS;

        // ---- compute pass: update dd, float-track per-thread best (dist,idx) ----
        float bd = -1.0f;
        unsigned int bj = 0;
#pragma unroll
        for (int k = 0; k < PPT; k++) {
            int j = gid + k * NTOT;
            // IEEE ops in reference order; _rn intrinsics block fp-contract
            float dx = __fsub_rn(px[k], qx);
            float dy = __fsub_rn(py[k], qy);
            float dz = __fsub_rn(pz[k], qz);
            float d  = __fadd_rn(__fadd_rn(__fmul_rn(dx, dx), __fmul_rn(dy, dy)),
                                 __fmul_rn(dz, dz));
            float nd = fminf(dd[k], d);
            dd[k] = nd;
            // strict > keeps the smallest j on ties (j ascends with k)
            bool upd = (nd > bd);
            if (k == PPT - 1) upd = upd && (gid < TAIL_GID);
            bd = upd ? nd : bd;
            bj = upd ? (unsigned int)j : bj;
        }
        unsigned long long key =
            ((unsigned long long)__float_as_uint(bd) << 32) |
            (tg << 19) |
            (unsigned long long)(N_POINTS - bj);

        // ---- per-wave DPP reduce, stage into LDS ----
        unsigned long long wmax = wave_scan_max_u64<6, 63>(key);
        if (lane == 0) s_wmax[wid] = wmax;
        __syncthreads();

        if (wid == 0) {
            // ---- block reduce: 8 wave maxima -> wave-uniform blockmax;
            //      lanes 0-3 store the SAME word to 4 private lines (one
            //      store instruction, 4 visibility paths in parallel) ----
            unsigned long long bk = (lane < NWAVE) ? s_wmax[lane] : 0ull;
            unsigned long long blockmax = wave_scan_max_u64<3, 7>(bk);
            if (lane < NREP)
                __hip_atomic_store(&cur[(size_t)bid * EWORDS + lane * 8],
                                   blockmax,
                                   __ATOMIC_RELAXED, __HIP_MEMORY_SCOPE_AGENT);

            // ---- STAGGERED 4-address poll: lane l watches block l's 4
            //      replica lines. Initial issues offset ~320 cy (s_sleep(5));
            //      in the loop each check is gated by its own address's
            //      return (vmcnt), so the ~L/4 offsets self-maintain.
            //      Line sampled every ~max(320, L/4) instead of every ~L.
            //      Body is uniform, no other memory ops (R9/R10 lessons). ----
            const unsigned long long* lp = cur + (size_t)lane * EWORDS;
            unsigned long long e;
            unsigned long long v0 = FPS_AL(lp + 0);
            __builtin_amdgcn_s_sleep(5);
            unsigned long long v1 = FPS_AL(lp + 8);
            __builtin_amdgcn_s_sleep(5);
            unsigned long long v2 = FPS_AL(lp + 16);
            __builtin_amdgcn_s_sleep(5);
            unsigned long long v3 = FPS_AL(lp + 24);
            for (;;) {
                if (((v0 >> 19) & 255ull) == tg) { e = v0; break; }
                v0 = FPS_AL(lp + 0);
                if (((v1 >> 19) & 255ull) == tg) { e = v1; break; }
                v1 = FPS_AL(lp + 8);
                if (((v2 >> 19) & 255ull) == tg) { e = v2; break; }
                v2 = FPS_AL(lp + 16);
                if (((v3 >> 19) & 255ull) == tg) { e = v3; break; }
                v3 = FPS_AL(lp + 24);
            }

            // ---- speculative pivot fetch (R7-verified): each lane fetches
            //      ITS candidate's row; rows are IC-warm (all blocks fetch
            //      the same 64); latency overlaps the final DPP reduce ----
            unsigned int widx = N_POINTS - (unsigned int)(e & 0x7FFFFull);
            float4 pv = *reinterpret_cast<const float4*>(feats + (size_t)widx * WIDTH);

            unsigned long long win = wave_scan_max_u64<6, 63>(e);

            // Exactly one lane matches (entry indices are globally distinct)
            if (e == win) {
                s_qx = pv.x; s_qy = pv.y; s_qz = pv.z;
                if (bid == 0) out[i] = (int)widx;
            }
        }
        // Waves 1..7 wait here while wave 0 runs the exchange
        __syncthreads();
        qx = s_qx; qy = s_qy; qz = s_qz;
    }
}

extern "C" void kernel_launch(void* const* d_in, const int* in_sizes, int n_in,
                              void* d_out, int out_size, void* d_ws, size_t ws_size,
                              hipStream_t stream) {
    const float* feats = (const float*)d_in[0];
    int* out = (int*)d_out;
    unsigned long long* slot = (unsigned long long*)d_ws;  // 2 MiB used

    fps_init<<<(SLOT_WORDS + 255) / 256, 256, 0, stream>>>(slot, out);
    // 64 blocks x 512 thr: all blocks trivially co-resident
    fps_main<<<NBLK, NTHR, 0, stream>>>(feats, out, slot);
}

// Round 13
// 2242.460 us; speedup vs baseline: 1.1051x; 1.0659x over previous
//
#include <hip/hip_runtime.h>
#include <stdint.h>

#define N_POINTS   400000
#define WIDTH      64
#define M_SAMPLES  1000          // N_POINTS / 400
#define NBLK       64
#define NTHR       512
#define NWAVE      (NTHR / 64)   // 8 waves per block
#define NTOT       (NBLK * NTHR) // 32768 threads -> 2 waves/SIMD on 64 CUs
#define PPT        13            // ceil(400000 / 32768)
#define TAIL_GID   (N_POINTS - (PPT - 1) * NTOT)  // gid < this => k=12 valid
#define EPAD       8             // entry stride = 64 B = ONE cache line, ONE writer
#define NREG       128           // region rotation; reuse distance 128
#define SLOT_WORDS (NREG * NBLK * EPAD)   // 65536 words = 512 KiB

// ===== VERIFIED CHAMPION (R7: 2131 us counter / 2241 us wall) =====
// Entry (single 8-B word at the head of a PRIVATE 64-B line; ONE writer/line):
//   [63:32] dist f32 bits (non-negative -> monotone u32)
//   [26:19] tag = i & 255
//   [18:0]  N - idx (1..400000 < 2^19; ties -> lowest idx wins)
// Region r = (i-1) & 127. Stale entries are from i-128 (tag differs in bit 7);
// region r's first use is i = r+1 (tag != 0) so initial zeros never validate.
// Overwrite-before-gather impossible: storing region r at iteration i requires
// having gathered i-1, hence all blocks stored i-1, hence every block consumed
// region r's previous generation long ago.
//
// Exchange-design ledger (11 single-variable rounds on MI355X):
//   - one writer per 64-B line        WIN  (R5: -575 us; write-write ownership
//                                           ping-pong was the dominant term)
//   - few visibility events (64)      WIN  (R5 vs R6: 32/64 events beat 256)
//   - wide compute, 2 waves/SIMD      WIN  (R7: -464 us vs 32-CU config)
//   - traffic width (8x fewer stores) NULL (R4: latency floor, not BW)
//   - same-address pipelined poll     LOSS (R10: MSHR-merge -> same period +
//                                           rotation drain; dependent spin is
//                                           optimal for one address)
//   - divergent in-loop fetch         LOSS (R9: breaks static vmcnt -> +600 us)
//   - payload (xyz) in entry          LOSS (R1/R11: pivot rows are IC-warm,
//                                           fetch already hidden by reduce;
//                                           extra words cost more than saved)
//   - 4x replicated-line sampling     LOSS (R12: returns bunch at the IC, no
//                                           phase interleave; 2x FETCH for +150)
// Residual per-iteration cost ~5100 cy: ~570 compute + ~500 reduces/LDS/barriers
// + ~2500 store -> cross-XCD visibility -> spin detect + ~1500 skew/tail. This
// is the serial-exchange fabric floor for 999 dependent global argmaxes.

__global__ void fps_init(unsigned long long* slot, int* out) {
    int t = blockIdx.x * blockDim.x + threadIdx.x;
    if (t < SLOT_WORDS) slot[t] = 0ull;
    if (t == 0) out[0] = 0;      // seed index
}

// u64 max-reduce via DPP row-scan (HW-verified rounds 1-12).
// STAGES=3 + SRC=7  : max over lanes 0..7   (block-level, 8 wave maxima)
// STAGES=6 + SRC=63 : max over all 64 lanes
template <int STAGES, int SRCLANE>
__device__ inline unsigned long long wave_scan_max_u64(unsigned long long key) {
    unsigned int lo = (unsigned int)key;
    unsigned int hi = (unsigned int)(key >> 32);
#define FPS_DPP_STAGE(CTRL)                                                     \
    {                                                                           \
        unsigned int nlo = (unsigned int)__builtin_amdgcn_update_dpp(           \
            (int)lo, (int)lo, CTRL, 0xf, 0xf, false);                           \
        unsigned int nhi = (unsigned int)__builtin_amdgcn_update_dpp(           \
            (int)hi, (int)hi, CTRL, 0xf, 0xf, false);                           \
        unsigned long long cand = ((unsigned long long)nhi << 32) | nlo;        \
        unsigned long long cur  = ((unsigned long long)hi  << 32) | lo;         \
        if (cand > cur) { lo = nlo; hi = nhi; }                                 \
    }
    if constexpr (STAGES > 0) FPS_DPP_STAGE(0x111)  // row_shr:1
    if constexpr (STAGES > 1) FPS_DPP_STAGE(0x112)  // row_shr:2
    if constexpr (STAGES > 2) FPS_DPP_STAGE(0x114)  // row_shr:4
    if constexpr (STAGES > 3) FPS_DPP_STAGE(0x118)  // row_shr:8
    if constexpr (STAGES > 4) FPS_DPP_STAGE(0x142)  // row_bcast15
    if constexpr (STAGES > 5) FPS_DPP_STAGE(0x143)  // row_bcast31
#undef FPS_DPP_STAGE
    unsigned int rlo = (unsigned int)__builtin_amdgcn_readlane((int)lo, SRCLANE);
    unsigned int rhi = (unsigned int)__builtin_amdgcn_readlane((int)hi, SRCLANE);
    return ((unsigned long long)rhi << 32) | rlo;
}

// Workspace requirement: SLOT_WORDS * 8 B = 524,288 B in d_ws.
__global__ __launch_bounds__(NTHR)
void fps_main(const float* __restrict__ feats, int* __restrict__ out,
              unsigned long long* __restrict__ slot)
{
    const int tid  = threadIdx.x;
    const int bid  = blockIdx.x;
    const int lane = tid & 63;
    const int wid  = tid >> 6;
    const int gid  = bid * NTHR + tid;

    // Register-resident points + running min squared distance
    float px[PPT], py[PPT], pz[PPT], dd[PPT];
#pragma unroll
    for (int k = 0; k < PPT; k++) {
        int j = gid + k * NTOT;
        if (j < N_POINTS) {
            // row start is 256-B aligned -> one dwordx4 gets x,y,z(,w)
            float4 v = *reinterpret_cast<const float4*>(feats + (size_t)j * WIDTH);
            px[k] = v.x; py[k] = v.y; pz[k] = v.z;
        } else {
            px[k] = 0.f; py[k] = 0.f; pz[k] = 0.f;
        }
        dd[k] = 1e10f;          // matches jnp.full(..., 1e10, f32)
    }

    __shared__ unsigned long long s_wmax[NWAVE];
    __shared__ float s_qx, s_qy, s_qz;

    // Iteration-1 pivot = point 0 (bit-identical source values)
    float qx = feats[0];
    float qy = feats[1];
    float qz = feats[2];

    for (int i = 1; i < M_SAMPLES; i++) {
        const unsigned long long tg = (unsigned long long)(i & 255);
        unsigned long long* cur = slot + (size_t)((i - 1) & (NREG - 1)) * NBLK * EPAD;

        // ---- compute pass: update dd, float-track per-thread best (dist,idx) ----
        float bd = -1.0f;
        unsigned int bj = 0;
#pragma unroll
        for (int k = 0; k < PPT; k++) {
            int j = gid + k * NTOT;
            // IEEE ops in reference order; _rn intrinsics block fp-contract
            float dx = __fsub_rn(px[k], qx);
            float dy = __fsub_rn(py[k], qy);
            float dz = __fsub_rn(pz[k], qz);
            float d  = __fadd_rn(__fadd_rn(__fmul_rn(dx, dx), __fmul_rn(dy, dy)),
                                 __fmul_rn(dz, dz));
            float nd = fminf(dd[k], d);
            dd[k] = nd;
            // strict > keeps the smallest j on ties (j ascends with k)
            bool upd = (nd > bd);
            if (k == PPT - 1) upd = upd && (gid < TAIL_GID);
            bd = upd ? nd : bd;
            bj = upd ? (unsigned int)j : bj;
        }
        unsigned long long key =
            ((unsigned long long)__float_as_uint(bd) << 32) |
            (tg << 19) |
            (unsigned long long)(N_POINTS - bj);

        // ---- per-wave DPP reduce, stage into LDS ----
        unsigned long long wmax = wave_scan_max_u64<6, 63>(key);
        if (lane == 0) s_wmax[wid] = wmax;
        __syncthreads();

        if (wid == 0) {
            // ---- block reduce: 8 wave maxima -> ONE store to a private line ----
            unsigned long long bk = (lane < NWAVE) ? s_wmax[lane] : 0ull;
            unsigned long long blockmax = wave_scan_max_u64<3, 7>(bk);
            if (lane == 0)
                __hip_atomic_store(&cur[(size_t)bid * EPAD], blockmax,
                                   __ATOMIC_RELAXED, __HIP_MEMORY_SCOPE_AGENT);

            // ---- DEPENDENT-SPIN poll: lane l waits on block l's entry.
            // One outstanding load per lane; uniform body; optimal for a
            // single address (R10: pipelining merges in the MSHR and loses;
            // R12: multi-line replication bunches at the IC and loses). ----
            const unsigned long long* lp = cur + (size_t)lane * EPAD;
            unsigned long long e;
            do {
                e = __hip_atomic_load(lp, __ATOMIC_RELAXED,
                                      __HIP_MEMORY_SCOPE_AGENT);
            } while (((e >> 19) & 255ull) != tg);

            // ---- speculative pivot fetch: each lane fetches ITS candidate's
            //      row (IC-warm: all 64 blocks touch the same 64 rows);
            //      latency overlaps the final DPP reduce ----
            unsigned int widx = N_POINTS - (unsigned int)(e & 0x7FFFFull);
            float4 pv = *reinterpret_cast<const float4*>(feats + (size_t)widx * WIDTH);

            unsigned long long win = wave_scan_max_u64<6, 63>(e);

            // Exactly one lane matches (entry indices are globally distinct)
            if (e == win) {
                s_qx = pv.x; s_qy = pv.y; s_qz = pv.z;
                if (bid == 0) out[i] = (int)widx;
            }
        }
        // Waves 1..7 wait here while wave 0 runs the exchange
        __syncthreads();
        qx = s_qx; qy = s_qy; qz = s_qz;
    }
}

extern "C" void kernel_launch(void* const* d_in, const int* in_sizes, int n_in,
                              void* d_out, int out_size, void* d_ws, size_t ws_size,
                              hipStream_t stream) {
    const float* feats = (const float*)d_in[0];
    int* out = (int*)d_out;
    unsigned long long* slot = (unsigned long long*)d_ws;  // 512 KiB used

    fps_init<<<(SLOT_WORDS + 255) / 256, 256, 0, stream>>>(slot, out);
    // 64 blocks x 512 thr: all blocks trivially co-resident
    fps_main<<<NBLK, NTHR, 0, stream>>>(feats, out, slot);
}